// Round 8
// baseline (34.236 us; speedup 1.0000x reference)
//
#include <hip/hip_runtime.h>
#include <hip/hip_bf16.h>

#define NPTS 2048      // N == M == 2048
#define QMIX 8
#define LATD 64
#define IT   32        // i-rows per pair block (two half-passes of 16)
#define HIT  16
#define FSTRIDE 72     // floats per feature row (64 coeff + 6 dup coords + pad)

typedef float v2f __attribute__((ext_vector_type(2)));

__device__ __forceinline__ float softplus_f(float x) {
    return fmaxf(x, 0.0f) + log1pf(expf(-fabsf(x)));
}
__device__ __forceinline__ float selu_f(float z) {
    const float sc = 1.0507009873554805f;   // selu scale
    const float sa = 1.7580993408473766f;   // scale * alpha
    return (z > 0.0f) ? sc * z : sa * expm1f(z);
}

// Unified feature buffer F[4096][FSTRIDE]: rows 0..2047 = X points,
// rows 2048..4095 = Y points. Per row:
//   [ (q>>1)*16 + k*2 + (q&1) ] for k=0..7:
//     k: [EF*A00, EF*A11, EF*A22, 2EF*A01, 2EF*A02, 2EF*A12, w*cos, w*sin]
//     (EF = sqrt(5)*log2(e) folded in; u = EF*r, exp(-sqrt5 r) = exp2(-u))
//   [64..69] = {p0,p0, p1,p1, p2,p2}  (duplicated coords -> pk operands)
// The {q0,q1} interleave makes every 8-byte coefficient load a legal 64-bit
// packed-fp32 operand (v_pk_*_f32), with no per-use splat.
__global__ __launch_bounds__(640) void feat_kernel(
    const float* __restrict__ xin, const float* __restrict__ yin,
    const float* __restrict__ W1, const float* __restrict__ b1,
    const float* __restrict__ Ww, const float* __restrict__ bw,
    const float* __restrict__ Wf, const float* __restrict__ bf,
    const float* __restrict__ Ws, const float* __restrict__ bs,
    float* __restrict__ F)
{
    __shared__ float hsh[8][LATD + 4];   // padded: conflict-free per-lane reads
    __shared__ float raw[8][80];         // head outputs per local point
    const int t = threadIdx.x;

    // phase 1: h = selu(W1 @ p + b1); t -> (l = t>>3, pl = t&7)
    if (t < 512) {
        const int pl = t & 7, l = t >> 3;
        const int g = blockIdx.x * 8 + pl;
        const bool isx = (g < NPTS);
        const float* pts = isx ? (xin + 3 * g) : (yin + 3 * (g - NPTS));
        const float z = fmaf(W1[l * 3 + 0], pts[0],
                        fmaf(W1[l * 3 + 1], pts[1],
                        fmaf(W1[l * 3 + 2], pts[2], b1[l])));
        hsh[pl][l] = selu_f(z);
    }
    __syncthreads();

    // phase 2: t -> (o = t>>3, pl = t&7); o = q*10 + e
    {
        const int o  = t >> 3;
        const int pl = t & 7;
        const int q  = o / 10;
        const int e  = o % 10;
        const float* row;
        float acc;
        if (e == 0)      { row = Ww + q * LATD;                 acc = bw[q]; }
        else if (e <= 3) { row = Wf + (q * 3 + (e - 1)) * LATD; acc = bf[q * 3 + (e - 1)]; }
        else             { row = Ws + (q * 6 + (e - 4)) * LATD; acc = bs[q * 6 + (e - 4)]; }
#pragma unroll
        for (int l4 = 0; l4 < LATD / 4; ++l4) {
            const float4 rv = reinterpret_cast<const float4*>(row)[l4];
            const float4 hv = *reinterpret_cast<const float4*>(&hsh[pl][l4 * 4]);
            acc = fmaf(rv.x, hv.x, acc);
            acc = fmaf(rv.y, hv.y, acc);
            acc = fmaf(rv.z, hv.z, acc);
            acc = fmaf(rv.w, hv.w, acc);
        }
        raw[pl][o] = softplus_f(acc);
    }
    __syncthreads();

    // phase 3: assemble per-(point,q) coefficients into the unified layout
    if (t < 64) {
        const int pl2 = t >> 3, q2 = t & 7;
        const int g2  = blockIdx.x * 8 + pl2;
        const bool isx2 = (g2 < NPTS);
        const float* pts2 = isx2 ? (xin + 3 * g2) : (yin + 3 * (g2 - NPTS));
        const float c0 = pts2[0], c1 = pts2[1], c2 = pts2[2];
        const float* r = raw[pl2] + q2 * 10;
        const float w  = r[0];
        const float f0 = r[1], f1 = r[2], f2 = r[3];
        const float s0 = r[4], s1 = r[5], s2 = r[6];
        const float s3 = r[7], s4 = r[8], s5 = r[9];

        // A = L L^T, L = [[s0,0,0],[s1,s2,0],[s3,s4,s5]]
        const float A00 = s0 * s0;
        const float A11 = fmaf(s1, s1, s2 * s2);
        const float A22 = fmaf(s3, s3, fmaf(s4, s4, s5 * s5));
        const float A01 = s0 * s1;
        const float A02 = s0 * s3;
        const float A12 = fmaf(s1, s3, s2 * s4);
        const float ph  = fmaf(f0, c0, fmaf(f1, c1, f2 * c2));
        float sn, cs;
        sincosf(6.283185307179586477f * ph, &sn, &cs);

        const float EF  = 3.2259751249059600974f;  // sqrt(5) * log2(e)
        const float EF2 = 2.0f * EF;
        const float vals[8] = { EF * A00, EF * A11, EF * A22,
                                EF2 * A01, EF2 * A02, EF2 * A12,
                                w * cs, w * sn };
        float* o = F + (size_t)g2 * FSTRIDE;
        const int base = (q2 >> 1) * 16 + (q2 & 1);
#pragma unroll
        for (int k = 0; k < 8; ++k) o[base + k * 2] = vals[k];
        if (q2 == 0) {
            o[64] = c0; o[65] = c0;
            o[66] = c1; o[67] = c1;
            o[68] = c2; o[69] = c2;
        }
    }
}

// Pair kernel: thread owns one j column; its 4 mixture components are
// processed as 2 packed q-pairs (v2f lanes = {q_even, q_odd}). X-row data is
// wave-uniform -> compiler emits s_load; the 8-byte {q0,q1} coefficient pairs
// and duplicated coords are direct 64-bit operands for v_pk_*_f32 (no splats
// anywhere in the hot loop). q-halves merged via a small LDS reduction.
__global__ __launch_bounds__(256, 4) void pair_kernel(
    const float* __restrict__ F, float* __restrict__ out)
{
    __shared__ float red[HIT][128];       // 8 KB
    const int t    = threadIdx.x;
    const int wave = __builtin_amdgcn_readfirstlane(t >> 6);  // uniform
    const int lane = t & 63;
    const int qg   = wave & 1;            // q-half: 0 -> q0..3, 1 -> q4..7
    const int jh   = wave >> 1;           // j-half of the block
    const int jl   = jh * 64 + lane;      // local j 0..127
    const int j    = blockIdx.x * 128 + jl;
    const int i0   = blockIdx.y * IT;

    // Y features for this thread's 4 q's (2 packed q-pairs) + dup'd coords
    const float* __restrict__ frow = F + (size_t)(NPTS + j) * FSTRIDE;
    v2f fy[16];
    {
        const float4* fp = reinterpret_cast<const float4*>(frow + qg * 32);
#pragma unroll
        for (int n = 0; n < 8; ++n) {
            const float4 v = fp[n];
            fy[2 * n + 0] = v2f{v.x, v.y};
            fy[2 * n + 1] = v2f{v.z, v.w};
        }
    }
    const v2f yd0 = *reinterpret_cast<const v2f*>(frow + 64);
    const v2f yd1 = *reinterpret_cast<const v2f*>(frow + 66);
    const v2f yd2 = *reinterpret_cast<const v2f*>(frow + 68);

    const float P1 = 0.69314718055994530942f;  // ln2       (t = u*ln2)
    const float P2 = 0.16013630893549922444f;  // ln2^2/3
    const float* __restrict__ fxb = F + (size_t)i0 * FSTRIDE;  // uniform base

#pragma unroll
    for (int half = 0; half < 2; ++half) {
        v2f acc[HIT];
#pragma unroll
        for (int i2 = 0; i2 < HIT; ++i2) {
            const float* __restrict__ fx = fxb + (half * HIT + i2) * FSTRIDE;
            // uniform 8-byte loads -> SGPR pairs
            const v2f xd0 = *reinterpret_cast<const v2f*>(fx + 64);
            const v2f xd1 = *reinterpret_cast<const v2f*>(fx + 66);
            const v2f xd2 = *reinterpret_cast<const v2f*>(fx + 68);
            const v2f d0 = yd0 - xd0;
            const v2f d1 = yd1 - xd1;
            const v2f d2 = yd2 - xd2;
            const v2f p00 = d0 * d0, p11 = d1 * d1, p22 = d2 * d2;
            const v2f p01 = d0 * d1, p02 = d0 * d2, p12 = d1 * d2;

            v2f a = v2f{0.f, 0.f};
#pragma unroll
            for (int qpl = 0; qpl < 2; ++qpl) {
                const v2f* __restrict__ c =
                    reinterpret_cast<const v2f*>(fx + (qg * 2 + qpl) * 16);
                v2f u;
                u  = (fy[qpl * 8 + 0] + c[0]) * p00;
                u += (fy[qpl * 8 + 1] + c[1]) * p11;
                u += (fy[qpl * 8 + 2] + c[2]) * p22;
                u += (fy[qpl * 8 + 3] + c[3]) * p01;
                u += (fy[qpl * 8 + 4] + c[4]) * p02;
                u += (fy[qpl * 8 + 5] + c[5]) * p12;
                // u = EF*r;  mat = (1 + t + t^2/3)*exp(-t), t = u*ln2
                const v2f poly = u * (u * P2 + P1) + 1.0f;
                const v2f ex = v2f{__builtin_amdgcn_exp2f(-u.x),
                                   __builtin_amdgcn_exp2f(-u.y)};
                v2f ct = fy[qpl * 8 + 6] * c[6];
                ct += fy[qpl * 8 + 7] * c[7];
                a += (poly * ex) * ct;
            }
            acc[i2] = a;
        }

        // merge q-halves: qg1 publishes (horizontal-added), qg0 adds + stores
        if (qg == 1) {
#pragma unroll
            for (int i2 = 0; i2 < HIT; ++i2)
                red[i2][jl] = acc[i2].x + acc[i2].y;
        }
        __syncthreads();
        if (qg == 0) {
#pragma unroll
            for (int i2 = 0; i2 < HIT; ++i2) {
                out[(size_t)(i0 + half * HIT + i2) * NPTS + j] =
                    acc[i2].x + acc[i2].y + red[i2][jl];
            }
        }
        __syncthreads();   // red reused by next half-pass
    }
}

extern "C" void kernel_launch(void* const* d_in, const int* in_sizes, int n_in,
                              void* d_out, int out_size, void* d_ws, size_t ws_size,
                              hipStream_t stream) {
    const float* x  = (const float*)d_in[0];
    const float* y  = (const float*)d_in[1];
    const float* W1 = (const float*)d_in[2];
    const float* b1 = (const float*)d_in[3];
    const float* Ww = (const float*)d_in[4];
    const float* bw = (const float*)d_in[5];
    const float* Wf = (const float*)d_in[6];
    const float* bf = (const float*)d_in[7];
    const float* Ws = (const float*)d_in[8];
    const float* bs = (const float*)d_in[9];
    float* out = (float*)d_out;

    float* F = (float*)d_ws;   // 4096 * FSTRIDE floats (~1.2 MB)

    // features: 4096 points, 8 per block
    feat_kernel<<<dim3((2 * NPTS) / 8), dim3(640), 0, stream>>>(
        x, y, W1, b1, Ww, bw, Wf, bf, Ws, bs, F);

    // pairwise: (16 j-blocks of 128 columns, 64 i-blocks of 32 rows)
    pair_kernel<<<dim3(NPTS / 128, NPTS / IT), dim3(256), 0, stream>>>(F, out);
}

// Round 9
// 34.201 us; speedup vs baseline: 1.0010x; 1.0010x over previous
//
#include <hip/hip_runtime.h>
#include <hip/hip_bf16.h>

#define NPTS 2048      // N == M == 2048
#define QMIX 8
#define LATD 64
#define IT   32        // i-rows per pair block
#define HIT  8         // i-rows per merge phase
#define NPH  (IT / HIT)
#define FXS  72        // floats per FX row: 64 coeff + 3 coords + pad
#define FYS  136       // floats per FYI j-pair row: 128 coeff + 6 dup coords + pad

typedef float v2f __attribute__((ext_vector_type(2)));

__device__ __forceinline__ float softplus_f(float x) {
    return fmaxf(x, 0.0f) + log1pf(expf(-fabsf(x)));
}
__device__ __forceinline__ float selu_f(float z) {
    const float sc = 1.0507009873554805f;   // selu scale
    const float sa = 1.7580993408473766f;   // scale * alpha
    return (z > 0.0f) ? sc * z : sa * expm1f(z);
}

// Coefficient meaning, k = 0..7 per (point, q):
//   [EF*A00, EF*A11, EF*A22, 2EF*A01, 2EF*A02, 2EF*A12, w*cos, w*sin]
// (EF = sqrt(5)*log2(e) folded in; u = EF*r, exp(-sqrt5 r) = exp2(-u)).
// FX  row (X point i):   [q*8+k] k-major per q, coords at [64..66]
// FYI row (Y j-pair jp): [q*16 + k*2 + (j&1)], dup coords at [128+c*2+(j&1)]
__global__ __launch_bounds__(640) void feat_kernel(
    const float* __restrict__ xin, const float* __restrict__ yin,
    const float* __restrict__ W1, const float* __restrict__ b1,
    const float* __restrict__ Ww, const float* __restrict__ bw,
    const float* __restrict__ Wf, const float* __restrict__ bf,
    const float* __restrict__ Ws, const float* __restrict__ bs,
    float* __restrict__ FX, float* __restrict__ FYI)
{
    __shared__ float hsh[8][LATD + 4];   // padded: conflict-free per-lane reads
    __shared__ float raw[8][80];         // head outputs per local point
    const int t = threadIdx.x;

    // phase 1: h = selu(W1 @ p + b1); t -> (l = t>>3, pl = t&7)
    if (t < 512) {
        const int pl = t & 7, l = t >> 3;
        const int g = blockIdx.x * 8 + pl;
        const bool isx = (g < NPTS);
        const float* pts = isx ? (xin + 3 * g) : (yin + 3 * (g - NPTS));
        const float z = fmaf(W1[l * 3 + 0], pts[0],
                        fmaf(W1[l * 3 + 1], pts[1],
                        fmaf(W1[l * 3 + 2], pts[2], b1[l])));
        hsh[pl][l] = selu_f(z);
    }
    __syncthreads();

    // phase 2: t -> (o = t>>3, pl = t&7); o = q*10 + e
    {
        const int o  = t >> 3;
        const int pl = t & 7;
        const int q  = o / 10;
        const int e  = o % 10;
        const float* row;
        float acc;
        if (e == 0)      { row = Ww + q * LATD;                 acc = bw[q]; }
        else if (e <= 3) { row = Wf + (q * 3 + (e - 1)) * LATD; acc = bf[q * 3 + (e - 1)]; }
        else             { row = Ws + (q * 6 + (e - 4)) * LATD; acc = bs[q * 6 + (e - 4)]; }
#pragma unroll
        for (int l4 = 0; l4 < LATD / 4; ++l4) {
            const float4 rv = reinterpret_cast<const float4*>(row)[l4];
            const float4 hv = *reinterpret_cast<const float4*>(&hsh[pl][l4 * 4]);
            acc = fmaf(rv.x, hv.x, acc);
            acc = fmaf(rv.y, hv.y, acc);
            acc = fmaf(rv.z, hv.z, acc);
            acc = fmaf(rv.w, hv.w, acc);
        }
        raw[pl][o] = softplus_f(acc);
    }
    __syncthreads();

    // phase 3: assemble per-(point,q) coefficients
    if (t < 64) {
        const int pl2 = t >> 3, q2 = t & 7;
        const int g2  = blockIdx.x * 8 + pl2;
        const bool isx2 = (g2 < NPTS);
        const float* pts2 = isx2 ? (xin + 3 * g2) : (yin + 3 * (g2 - NPTS));
        const float c0 = pts2[0], c1 = pts2[1], c2 = pts2[2];
        const float* r = raw[pl2] + q2 * 10;
        const float w  = r[0];
        const float f0 = r[1], f1 = r[2], f2 = r[3];
        const float s0 = r[4], s1 = r[5], s2 = r[6];
        const float s3 = r[7], s4 = r[8], s5 = r[9];

        // A = L L^T, L = [[s0,0,0],[s1,s2,0],[s3,s4,s5]]
        const float A00 = s0 * s0;
        const float A11 = fmaf(s1, s1, s2 * s2);
        const float A22 = fmaf(s3, s3, fmaf(s4, s4, s5 * s5));
        const float A01 = s0 * s1;
        const float A02 = s0 * s3;
        const float A12 = fmaf(s1, s3, s2 * s4);
        const float ph  = fmaf(f0, c0, fmaf(f1, c1, f2 * c2));
        float sn, cs;
        sincosf(6.283185307179586477f * ph, &sn, &cs);

        const float EF  = 3.2259751249059600974f;  // sqrt(5) * log2(e)
        const float EF2 = 2.0f * EF;
        const float vals[8] = { EF * A00, EF * A11, EF * A22,
                                EF2 * A01, EF2 * A02, EF2 * A12,
                                w * cs, w * sn };
        if (isx2) {
            float* o = FX + (size_t)g2 * FXS + q2 * 8;
            reinterpret_cast<float4*>(o)[0] = make_float4(vals[0], vals[1], vals[2], vals[3]);
            reinterpret_cast<float4*>(o)[1] = make_float4(vals[4], vals[5], vals[6], vals[7]);
            if (q2 == 0) {
                float* oc = FX + (size_t)g2 * FXS + 64;
                oc[0] = c0; oc[1] = c1; oc[2] = c2;
            }
        } else {
            const int pi = g2 - NPTS;
            float* o = FYI + (size_t)(pi >> 1) * FYS + q2 * 16 + (pi & 1);
#pragma unroll
            for (int k = 0; k < 8; ++k) o[k * 2] = vals[k];
            if (q2 == 0) {
                float* oc = FYI + (size_t)(pi >> 1) * FYS + 128 + (pi & 1);
                oc[0] = c0; oc[2] = c1; oc[4] = c2;
            }
        }
    }
}

// Pair kernel: block = 4 waves, all covering the same 128 j columns; wave qg
// owns q = {2qg, 2qg+1}. Each thread owns a j-PAIR (v2f lanes {j0,j1}) and
// 2 mixture components: fy = 16 v2f = 32 VGPR, acc = 8 v2f = 16 VGPR, so the
// kernel stays well under the 128-VGPR / 4-waves-per-SIMD cap (NO SPILLS).
// X-row coefficients+coords are wave-uniform C++ loads -> scalar-pipe s_load,
// consumed as SGPR broadcast operands. 4-way q-merge via 12 KB LDS.
__global__ __launch_bounds__(256, 4) void pair_kernel(
    const float* __restrict__ FX, const float* __restrict__ FYI,
    float* __restrict__ out)
{
    __shared__ v2f red[3][HIT][64];       // 12 KB
    const int t    = threadIdx.x;
    const int qg   = __builtin_amdgcn_readfirstlane(t >> 6); // wave id = q-group
    const int lane = t & 63;
    const int jp   = blockIdx.x * 64 + lane;   // j-pair index
    const int j0   = jp * 2;
    const int i0   = blockIdx.y * IT;

    // Y features for this wave's 2 q's: 8 float4 -> 16 v2f ({j0,j1} packed)
    const float* __restrict__ frow = FYI + (size_t)jp * FYS;
    v2f fy[16];
    {
        const float4* fp = reinterpret_cast<const float4*>(frow + qg * 32);
#pragma unroll
        for (int m = 0; m < 8; ++m) {
            const float4 v = fp[m];
            fy[2 * m + 0] = v2f{v.x, v.y};
            fy[2 * m + 1] = v2f{v.z, v.w};
        }
    }
    const v2f yc0 = *reinterpret_cast<const v2f*>(frow + 128);
    const v2f yc1 = *reinterpret_cast<const v2f*>(frow + 130);
    const v2f yc2 = *reinterpret_cast<const v2f*>(frow + 132);

    const float P1 = 0.69314718055994530942f;  // ln2       (t = u*ln2)
    const float P2 = 0.16013630893549922444f;  // ln2^2/3

    for (int ph = 0; ph < NPH; ++ph) {
        v2f acc[HIT];
#pragma unroll
        for (int i2 = 0; i2 < HIT; ++i2) acc[i2] = v2f{0.f, 0.f};

#pragma unroll
        for (int i2 = 0; i2 < HIT; ++i2) {
            // wave-uniform X row: scalar-pipe loads
            const float* __restrict__ fx =
                FX + (size_t)(i0 + ph * HIT + i2) * FXS;
            const float x0 = fx[64], x1 = fx[65], x2 = fx[66];
            const v2f d0 = yc0 - x0;
            const v2f d1 = yc1 - x1;
            const v2f d2 = yc2 - x2;
            const v2f p00 = d0 * d0, p11 = d1 * d1, p22 = d2 * d2;
            const v2f p01 = d0 * d1, p02 = d0 * d2, p12 = d1 * d2;

#pragma unroll
            for (int ql = 0; ql < 2; ++ql) {
                const float* __restrict__ c = fx + (qg * 2 + ql) * 8;
                v2f u;
                u  = (fy[ql * 8 + 0] + c[0]) * p00;
                u += (fy[ql * 8 + 1] + c[1]) * p11;
                u += (fy[ql * 8 + 2] + c[2]) * p22;
                u += (fy[ql * 8 + 3] + c[3]) * p01;
                u += (fy[ql * 8 + 4] + c[4]) * p02;
                u += (fy[ql * 8 + 5] + c[5]) * p12;
                // u = EF*r;  mat = (1 + t + t^2/3)*exp(-t), t = u*ln2
                const v2f poly = u * (u * P2 + P1) + 1.0f;
                const v2f ex = v2f{__builtin_amdgcn_exp2f(-u.x),
                                   __builtin_amdgcn_exp2f(-u.y)};
                v2f ct = fy[ql * 8 + 6] * c[6];
                ct += fy[ql * 8 + 7] * c[7];
                acc[i2] += (poly * ex) * ct;
            }
        }

        // 4-way q-merge: waves 1..3 publish, wave 0 sums and stores
        if (qg != 0) {
#pragma unroll
            for (int i2 = 0; i2 < HIT; ++i2) red[qg - 1][i2][lane] = acc[i2];
        }
        __syncthreads();
        if (qg == 0) {
#pragma unroll
            for (int i2 = 0; i2 < HIT; ++i2) {
                const v2f s = acc[i2] + red[0][i2][lane]
                            + red[1][i2][lane] + red[2][i2][lane];
                *reinterpret_cast<float2*>(
                    out + (size_t)(i0 + ph * HIT + i2) * NPTS + j0) =
                    make_float2(s.x, s.y);
            }
        }
        __syncthreads();   // red reused next phase
    }
}

extern "C" void kernel_launch(void* const* d_in, const int* in_sizes, int n_in,
                              void* d_out, int out_size, void* d_ws, size_t ws_size,
                              hipStream_t stream) {
    const float* x  = (const float*)d_in[0];
    const float* y  = (const float*)d_in[1];
    const float* W1 = (const float*)d_in[2];
    const float* b1 = (const float*)d_in[3];
    const float* Ww = (const float*)d_in[4];
    const float* bw = (const float*)d_in[5];
    const float* Wf = (const float*)d_in[6];
    const float* bf = (const float*)d_in[7];
    const float* Ws = (const float*)d_in[8];
    const float* bs = (const float*)d_in[9];
    float* out = (float*)d_out;

    float* FX  = (float*)d_ws;                      // 2048 * 72 floats (~590 KB)
    float* FYI = FX + (size_t)NPTS * FXS;           // 1024 * 136 floats (~557 KB)

    // features: 4096 points, 8 per block
    feat_kernel<<<dim3((2 * NPTS) / 8), dim3(640), 0, stream>>>(
        x, y, W1, b1, Ww, bw, Wf, bf, Ws, bs, FX, FYI);

    // pairwise: (16 j-blocks of 128 columns, 64 i-blocks of 32 rows)
    pair_kernel<<<dim3(NPTS / 128, NPTS / IT), dim3(256), 0, stream>>>(
        FX, FYI, out);
}